// Round 19
// baseline (201.984 us; speedup 1.0000x reference)
//
#include <hip/hip_runtime.h>
#include <stdint.h>

typedef float f32x4 __attribute__((ext_vector_type(4)));
typedef short s16x8 __attribute__((ext_vector_type(8)));
typedef short s16x4 __attribute__((ext_vector_type(4)));

__device__ __forceinline__ unsigned short f2bf(float f) {
    uint32_t u = __float_as_uint(f);
    u += 0x7FFFu + ((u >> 16) & 1u);   // round-to-nearest-even
    return (unsigned short)(u >> 16);
}

// async 16B/lane global->LDS DMA (wave-uniform LDS base + lane*16, per-lane gaddr)
__device__ __forceinline__ void g2l16(const short* g, short* l) {
    __builtin_amdgcn_global_load_lds(
        (const __attribute__((address_space(1))) uint32_t*)g,
        (__attribute__((address_space(3))) uint32_t*)l, 16, 0, 0);
}

// ---------- prep: normalize mem rows, emit MFMA-fragment-packed bf16 ----------
// packed frag (ct16,kb): 512 shorts at (ct16*(C/32)+kb)*512;
// short lane*8+j = B[col=ct16*16+(lane&15)][k=kb*32+(lane>>4)*8+j]
template<int C>
__device__ __forceinline__ void prep_body(const float* __restrict__ mp,
                                          short* __restrict__ nmp,
                                          int ct, short* stage) {
    const int tid = threadIdx.x;       // 256 threads
    const int row = tid >> 4;          // 0..15 (B column)
    const int c4  = tid & 15;
    constexpr int IT = C / 64;
    const f32x4* src = (const f32x4*)(mp + (size_t)(ct * 16 + row) * C);
    f32x4 vals[IT];
    float ss = 0.f;
#pragma unroll
    for (int i = 0; i < IT; ++i) {
        f32x4 v = src[c4 + 16 * i];
        vals[i] = v;
        ss += v.x * v.x + v.y * v.y + v.z * v.z + v.w * v.w;
    }
#pragma unroll
    for (int m = 1; m < 16; m <<= 1) ss += __shfl_xor(ss, m);
    const float inv = 1.f / fmaxf(sqrtf(ss), 1e-12f);
#pragma unroll
    for (int i = 0; i < IT; ++i) {
        f32x4 v = vals[i];
        s16x4 o;
        o[0] = (short)f2bf(v.x * inv);
        o[1] = (short)f2bf(v.y * inv);
        o[2] = (short)f2bf(v.z * inv);
        o[3] = (short)f2bf(v.w * inv);
        *(s16x4*)&stage[row * C + (c4 + 16 * i) * 4] = o;
    }
    __syncthreads();
    const int lane = tid & 63;
    const int wv = tid >> 6;
    constexpr int NKB = C / 32;
#pragma unroll
    for (int j = 0; j < NKB / 4; ++j) {
        const int kb = j * 4 + wv;
        const s16x8 v = *(const s16x8*)&stage[(lane & 15) * C + kb * 32 + (lane >> 4) * 8];
        *(s16x8*)&nmp[((size_t)ct * NKB + kb) * 512 + lane * 8] = v;
    }
}

__global__ __launch_bounds__(256) void prep_all(const float* m0, short* n0,
                                                const float* m1, short* n1,
                                                const float* m2, short* n2) {
    __shared__ short stage[16 * 1024];
    const int bid = blockIdx.x;
    if (bid < 64) prep_body<256>(m0, n0, bid, stage);
    else if (bid < 128) prep_body<512>(m1, n1, bid - 64, stage);
    else prep_body<1024>(m2, n2, bid - 128, stage);
}

// ---------- GEMM: BM=64 x BN=1024, 16 waves; B via gload_lds + counted vmcnt;
// A via reg->LDS dbuf with lgkm-only barriers. The f-copy + mf-zero streaming
// is folded into the K-loop as CACHED stores (retire at L2 ack ~300cyc — the
// R14 disaster was NT stores retiring at HBM speed). One store per iteration,
// issued youngest (after MFMA). Exact wait table for the new queue:
//   kb==0 -> vmcnt(5)          [DMA(1)x4 + store_v0 younger than DMA(0)]
//   odd kb<=NKB-5 -> vmcnt(7)  [store + DMA x4 + fnxt + store]
//   kb==NKB-3 -> vmcnt(6)      [no fnxt issued at NKB-4]
//   even kb>=2 -> vmcnt(6)     [A-fill consume pre-drains DMA(kb)]
//   kb==NKB-1 -> vmcnt(2)      [two trailing stores]
// f read exactly once (registers), f-copy written from regs: no tail re-read.
template<int C>
__device__ __forceinline__ void gemm_body(const float* __restrict__ feat,
                                          const float* __restrict__ memv,
                                          const short* __restrict__ nm,
                                          float* __restrict__ out_cat,
                                          float* __restrict__ out_w,
                                          int tile,
                                          short* __restrict__ Bst,   // 2 x 32768 shorts
                                          short* __restrict__ As,    // 2 x 4096 shorts
                                          float (*__restrict__ red)[64],
                                          float* __restrict__ rowT,
                                          float* __restrict__ rowL,
                                          float* __restrict__ invL,
                                          int* __restrict__ rowflag,
                                          int* __restrict__ anyflag) {
    constexpr int NKB = C / 32;          // MFMA K-steps
    constexpr int NCH = C / 64;          // A LDS chunks (64 k each)
    const int tid  = threadIdx.x;        // 0..1023
    const int w    = tid >> 6;           // wave 0..15
    const int lane = tid & 63;
    const int g    = lane >> 4;
    const int ml   = lane & 15;
    const int swz  = ml & 7;
    const int row0 = tile * 64;

    // A fill role: thread -> (row 0..63, f32x4 slot 0..15 of a 64-float chunk)
    const int frow = tid >> 4;
    const int fk4  = tid & 15;
    const float* fsrc = feat + (size_t)(row0 + frow) * C + fk4 * 4;
    float* fcpy = out_cat + (size_t)(row0 + frow) * (2 * C) + C + fk4 * 4;
    float* fzro = out_cat + (size_t)(row0 + frow) * (2 * C) + fk4 * 4;
    const f32x4 z4 = {0.f, 0.f, 0.f, 0.f};
    const int ldsW = frow * 64 + (((fk4 >> 1) ^ (frow & 7)) << 3) + (fk4 & 1) * 4;
    // B: wave w owns col-tiles w*4..w*4+3; wave-private LDS frags of 1 KB
    const short* nbG = nm + (size_t)(w * 4) * NKB * 512 + lane * 8;
    short* bD0 = Bst + (w * 4) * 512 + lane * 8;
    short* bD1 = Bst + 32768 + (w * 4) * 512 + lane * 8;

    if (tid == 0) *anyflag = 0;

    f32x4 acc[4][4];
#pragma unroll
    for (int r = 0; r < 4; ++r)
#pragma unroll
        for (int ct = 0; ct < 4; ++ct)
            acc[r][ct] = (f32x4){0.f, 0.f, 0.f, 0.f};

    float ss = 0.f;

    // ---- prologue: A loads first (oldest), then B DMAs, then v0 consume +
    // its cached f-copy store (youngest) ----
    const f32x4 v0 = *(const f32x4*)fsrc;
    f32x4 fnxt;
    if (NCH > 1) fnxt = *(const f32x4*)(fsrc + 64);
    __builtin_amdgcn_sched_barrier(0);
#pragma unroll
    for (int p = 0; p < 4; ++p)
        g2l16(nbG + (size_t)p * NKB * 512, bD0 + p * 512);
#pragma unroll
    for (int p = 0; p < 4; ++p)
        g2l16(nbG + ((size_t)p * NKB + 1) * 512, bD1 + p * 512);
    __builtin_amdgcn_sched_barrier(0);
    {
        ss += v0.x * v0.x + v0.y * v0.y + v0.z * v0.z + v0.w * v0.w;
        s16x4 o;
        o[0] = (short)f2bf(v0.x); o[1] = (short)f2bf(v0.y);
        o[2] = (short)f2bf(v0.z); o[3] = (short)f2bf(v0.w);
        *(s16x4*)&As[ldsW] = o;
        *(f32x4*)fcpy = v0;              // cached store (L2 ack)
    }
    asm volatile("s_waitcnt lgkmcnt(0)" ::: "memory");
    __builtin_amdgcn_s_barrier();
    asm volatile("" ::: "memory");

    // ---- K loop ----
    for (int kb = 0; kb < NKB; ++kb) {
        const int chunk = kb >> 1;
        f32x4 fold;                      // value consumed this iter (for store)
        const bool dofill = ((kb & 1) == 0 && chunk + 1 < NCH);
        if (dofill) {
            fold = fnxt;
            ss += fold.x * fold.x + fold.y * fold.y + fold.z * fold.z + fold.w * fold.w;
            s16x4 o;
            o[0] = (short)f2bf(fold.x); o[1] = (short)f2bf(fold.y);
            o[2] = (short)f2bf(fold.z); o[3] = (short)f2bf(fold.w);
            *(s16x4*)&As[((chunk + 1) & 1) * 4096 + ldsW] = o;
        }
        // counted wait (see table in header comment)
        if (kb == 0)                 asm volatile("s_waitcnt vmcnt(5)" ::: "memory");
        else if (kb == NKB - 1)      asm volatile("s_waitcnt vmcnt(2)" ::: "memory");
        else if (kb == NKB - 3)      asm volatile("s_waitcnt vmcnt(6)" ::: "memory");
        else if (kb & 1)             asm volatile("s_waitcnt vmcnt(7)" ::: "memory");
        else                         asm volatile("s_waitcnt vmcnt(6)" ::: "memory");
        // read own B frags + A frags from LDS
        const short* Bb = Bst + (kb & 1) * 32768 + (w * 4) * 512 + lane * 8;
        s16x8 b[4];
#pragma unroll
        for (int p = 0; p < 4; ++p)
            b[p] = *(const s16x8*)(Bb + p * 512);
        const short* Ab = &As[(chunk & 1) * 4096];
        const int gr = ((kb & 1) << 2) | g;
        s16x8 a[4];
#pragma unroll
        for (int r = 0; r < 4; ++r)
            a[r] = *(const s16x8*)&Ab[(r * 16 + ml) * 64 + ((gr ^ swz) << 3)];
        // drain LDS reads, then reuse this B buffer for kb+2's DMA
        asm volatile("s_waitcnt lgkmcnt(0)" ::: "memory");
        __builtin_amdgcn_sched_barrier(0);
        if (kb + 2 < NKB) {
            short* bDn = Bst + (kb & 1) * 32768 + (w * 4) * 512 + lane * 8;
#pragma unroll
            for (int p = 0; p < 4; ++p)
                g2l16(nbG + ((size_t)p * NKB + kb + 2) * 512, bDn + p * 512);
        }
        __builtin_amdgcn_sched_barrier(0);
        // fnxt HBM prefetch after the DMAs
        if ((kb & 1) == 0 && chunk + 2 < NCH)
            fnxt = *(const f32x4*)(fsrc + (size_t)(chunk + 2) * 64);
        __builtin_amdgcn_sched_barrier(0);
        __builtin_amdgcn_s_setprio(1);
#pragma unroll
        for (int r = 0; r < 4; ++r)
#pragma unroll
            for (int ct = 0; ct < 4; ++ct)
                acc[r][ct] = __builtin_amdgcn_mfma_f32_16x16x32_bf16(a[r], b[ct], acc[r][ct], 0, 0, 0);
        __builtin_amdgcn_s_setprio(0);
        __builtin_amdgcn_sched_barrier(0);
        // ONE cached output store per iteration, youngest in the queue:
        // even iters: f-copy of chunk+1 (from fold); odd iters: mf-zero of chunk
        if (kb & 1) {
            *(f32x4*)(fzro + (size_t)chunk * 64) = z4;
        } else if (dofill) {
            *(f32x4*)(fcpy + (size_t)(chunk + 1) * 64) = fold;
        } else {
            // kb == NKB-2: no fill left; store the last zero's twin slot here
            *(f32x4*)(fzro + (size_t)(NCH - 1) * 64) = z4;  // harmless pre-write; odd NKB-1 rewrites
        }
        __builtin_amdgcn_sched_barrier(0);
        // A barrier after odd kb (lgkm-only; DMAs + stores stay in flight)
        if ((kb & 1) == 1 && kb + 1 < NKB) {
            asm volatile("s_waitcnt lgkmcnt(0)" ::: "memory");
            __builtin_amdgcn_s_barrier();
            asm volatile("" ::: "memory");
        }
    }

    // ---- invn from own staged data ----
#pragma unroll
    for (int m = 1; m < 16; m <<= 1) ss += __shfl_xor(ss, m);
    if (fk4 == 0) invL[frow] = 1.f / fmaxf(sqrtf(ss), 1e-12f);
    __syncthreads();

    // C/D: global row = r*16 + 4*g + i, global col = (w*4+ct)*16 + ml
    // ---- exp (|cos|<=1: no max-sub) + row sums ----
#pragma unroll
    for (int r = 0; r < 4; ++r)
#pragma unroll
        for (int i = 0; i < 4; ++i) {
            const float inv = invL[r * 16 + 4 * g + i];
            float s = 0.f;
#pragma unroll
            for (int ct = 0; ct < 4; ++ct) {
                const float e = __expf(acc[r][ct][i] * inv);
                acc[r][ct][i] = e;
                s += e;
            }
#pragma unroll
            for (int m = 1; m < 16; m <<= 1) s += __shfl_xor(s, m);
            if (ml == 0) red[w][r * 16 + 4 * g + i] = s;
        }
    __syncthreads();
    if (tid < 64) {
        float t = red[0][tid];
#pragma unroll
        for (int ww = 1; ww < 16; ++ww) t += red[ww][tid];
        rowT[tid] = 1.f / t;
    }
    __syncthreads();

    // ---- softmax weight, hard-shrink, row L1 ----
#pragma unroll
    for (int r = 0; r < 4; ++r)
#pragma unroll
        for (int i = 0; i < 4; ++i) {
            const float tinv = rowT[r * 16 + 4 * g + i];
            float l1 = 0.f;
#pragma unroll
            for (int ct = 0; ct < 4; ++ct) {
                const float wv = acc[r][ct][i] * tinv;
                const float d = wv - 0.0025f;
                const float v = (d > 0.f) ? (d * wv / (d + 1e-12f)) : 0.f;
                acc[r][ct][i] = v;
                l1 += v;
            }
#pragma unroll
            for (int m = 1; m < 16; m <<= 1) l1 += __shfl_xor(l1, m);
            if (ml == 0) red[w][r * 16 + 4 * g + i] = l1;
        }
    __syncthreads();
    if (tid < 64) {
        float t = red[0][tid];
#pragma unroll
        for (int ww = 1; ww < 16; ++ww) t += red[ww][tid];
        rowL[tid] = 1.f / fmaxf(t, 1e-12f);
        rowflag[tid] = (t > 0.f) ? 1 : 0;
        if (t > 0.f) *anyflag = 1;
    }
    __syncthreads();                     // LAST barrier of the common path

    // ---- store W (cached; L2 assembles full lines). Nothing below waits on
    // vmcnt in the common path -> waves retire with stores in flight. ----
#pragma unroll
    for (int r = 0; r < 4; ++r)
#pragma unroll
        for (int i = 0; i < 4; ++i) {
            const float il = rowL[r * 16 + 4 * g + i];
            float* orow = out_w + (size_t)(row0 + r * 16 + 4 * g + i) * 1024;
#pragma unroll
            for (int ct = 0; ct < 4; ++ct)
                orow[(w * 4 + ct) * 16 + ml] = acc[r][ct][i] * il;
        }

    // ---- mf fixup ONLY when a row survived the shrink (rare path) ----
    if (*anyflag != 0) {
        __threadfence();
        __syncthreads();
        constexpr int CC = C / 64;
#pragma unroll
        for (int rr = 0; rr < 4; ++rr) {
            const int row = w * 4 + rr;
            if (!rowflag[row]) continue;
            float* dst = out_cat + (size_t)(row0 + row) * (2 * C);
            float mfacc[CC];
#pragma unroll
            for (int cc = 0; cc < CC; ++cc) mfacc[cc] = 0.f;
            const float* wrow = out_w + (size_t)(row0 + row) * 1024;
            for (int jb = 0; jb < 1024; jb += 64) {
                const float wv = wrow[jb + lane];
                unsigned long long msk = __ballot(wv != 0.f);
                while (msk) {
                    const int j = __builtin_ctzll(msk);
                    msk &= msk - 1;
                    const float val = __shfl(wv, j);
                    const float* mrow = memv + (size_t)(jb + j) * C;
#pragma unroll
                    for (int cc = 0; cc < CC; ++cc)
                        mfacc[cc] += val * mrow[cc * 64 + lane];
                }
            }
#pragma unroll
            for (int cc = 0; cc < CC; ++cc) dst[cc * 64 + lane] = mfacc[cc];
        }
    }
}

// unit-sorted: unit2 first (nm2 L2-hot), then unit1, unit0
__global__ __launch_bounds__(1024) void gemm_all(
        const float* f0, const float* m0, const short* n0, float* o0, float* w0,
        const float* f1, const float* m1, const short* n1, float* o1, float* w1,
        const float* f2, const float* m2, const short* n2, float* o2, float* w2) {
    __shared__ short Bst[2 * 32768];     // 2 x 64 KB B k-slabs (wave-private frags)
    __shared__ short As[2 * 4096];       // 2 x 8 KB A chunks
    __shared__ float red[16][64];
    __shared__ float rowT[64];
    __shared__ float rowL[64];
    __shared__ float invL[64];
    __shared__ int rowflag[64];
    __shared__ int anyflag;

    const int bid = blockIdx.x;
    if (bid < 256)
        gemm_body<1024>(f2, m2, n2, o2, w2, bid,
                        Bst, As, red, rowT, rowL, invL, rowflag, &anyflag);
    else if (bid < 512)
        gemm_body<512>(f1, m1, n1, o1, w1, bid - 256,
                       Bst, As, red, rowT, rowL, invL, rowflag, &anyflag);
    else
        gemm_body<256>(f0, m0, n0, o0, w0, bid - 512,
                       Bst, As, red, rowT, rowL, invL, rowflag, &anyflag);
}

extern "C" void kernel_launch(void* const* d_in, const int* in_sizes, int n_in,
                              void* d_out, int out_size, void* d_ws, size_t ws_size,
                              hipStream_t stream) {
    const float* feat[3] = {nullptr, nullptr, nullptr};
    const float* memp[3] = {nullptr, nullptr, nullptr};
    for (int i = 0; i < n_in && i < 6; ++i) {
        const int s = in_sizes[i];
        const float* p = (const float*)d_in[i];
        if (s == 16384 * 256) feat[0] = p;
        else if (s == 16384 * 512) feat[1] = p;
        else if (s == 16384 * 1024) feat[2] = p;
        else if (s == 1024 * 256) memp[0] = p;
        else if (s == 1024 * 512) memp[1] = p;
        else if (s == 1024 * 1024) memp[2] = p;
    }
    float* out = (float*)d_out;
    short* nm0 = (short*)d_ws;
    short* nm1 = nm0 + 1024 * 256;
    short* nm2 = nm1 + 1024 * 512;

    // output layout (floats): out0 | out1 | out2 | w0 | w1 | w2
    const size_t O0 = 0;
    const size_t O1 = (size_t)16384 * 512;
    const size_t O2 = O1 + (size_t)16384 * 1024;
    const size_t W0 = O2 + (size_t)16384 * 2048;
    const size_t W1 = W0 + (size_t)16384 * 1024;
    const size_t W2 = W1 + (size_t)16384 * 1024;

    prep_all<<<192, 256, 0, stream>>>(memp[0], nm0, memp[1], nm1, memp[2], nm2);

    gemm_all<<<768, 1024, 0, stream>>>(
        feat[0], memp[0], nm0, out + O0, out + W0,
        feat[1], memp[1], nm1, out + O1, out + W1,
        feat[2], memp[2], nm2, out + O2, out + W2);
}

// Round 20
// 172.795 us; speedup vs baseline: 1.1689x; 1.1689x over previous
//
#include <hip/hip_runtime.h>
#include <stdint.h>

typedef float f32x4 __attribute__((ext_vector_type(4)));
typedef short s16x8 __attribute__((ext_vector_type(8)));
typedef short s16x4 __attribute__((ext_vector_type(4)));

__device__ __forceinline__ unsigned short f2bf(float f) {
    uint32_t u = __float_as_uint(f);
    u += 0x7FFFu + ((u >> 16) & 1u);   // round-to-nearest-even
    return (unsigned short)(u >> 16);
}

// async 16B/lane global->LDS DMA (wave-uniform LDS base + lane*16, per-lane gaddr)
__device__ __forceinline__ void g2l16(const short* g, short* l) {
    __builtin_amdgcn_global_load_lds(
        (const __attribute__((address_space(1))) uint32_t*)g,
        (__attribute__((address_space(3))) uint32_t*)l, 16, 0, 0);
}

// ---------- prep: normalize mem rows, emit MFMA-fragment-packed bf16 ----------
// packed frag (ct16,kb): 512 shorts at (ct16*(C/32)+kb)*512;
// short lane*8+j = B[col=ct16*16+(lane&15)][k=kb*32+(lane>>4)*8+j]
template<int C>
__device__ __forceinline__ void prep_body(const float* __restrict__ mp,
                                          short* __restrict__ nmp,
                                          int ct, short* stage) {
    const int tid = threadIdx.x;       // 256 threads
    const int row = tid >> 4;          // 0..15 (B column)
    const int c4  = tid & 15;
    constexpr int IT = C / 64;
    const f32x4* src = (const f32x4*)(mp + (size_t)(ct * 16 + row) * C);
    f32x4 vals[IT];
    float ss = 0.f;
#pragma unroll
    for (int i = 0; i < IT; ++i) {
        f32x4 v = src[c4 + 16 * i];
        vals[i] = v;
        ss += v.x * v.x + v.y * v.y + v.z * v.z + v.w * v.w;
    }
#pragma unroll
    for (int m = 1; m < 16; m <<= 1) ss += __shfl_xor(ss, m);
    const float inv = 1.f / fmaxf(sqrtf(ss), 1e-12f);
#pragma unroll
    for (int i = 0; i < IT; ++i) {
        f32x4 v = vals[i];
        s16x4 o;
        o[0] = (short)f2bf(v.x * inv);
        o[1] = (short)f2bf(v.y * inv);
        o[2] = (short)f2bf(v.z * inv);
        o[3] = (short)f2bf(v.w * inv);
        *(s16x4*)&stage[row * C + (c4 + 16 * i) * 4] = o;
    }
    __syncthreads();
    const int lane = tid & 63;
    const int wv = tid >> 6;
    constexpr int NKB = C / 32;
#pragma unroll
    for (int j = 0; j < NKB / 4; ++j) {
        const int kb = j * 4 + wv;
        const s16x8 v = *(const s16x8*)&stage[(lane & 15) * C + kb * 32 + (lane >> 4) * 8];
        *(s16x8*)&nmp[((size_t)ct * NKB + kb) * 512 + lane * 8] = v;
    }
}

__global__ __launch_bounds__(256) void prep_all(const float* m0, short* n0,
                                                const float* m1, short* n1,
                                                const float* m2, short* n2) {
    __shared__ short stage[16 * 1024];
    const int bid = blockIdx.x;
    if (bid < 64) prep_body<256>(m0, n0, bid, stage);
    else if (bid < 128) prep_body<512>(m1, n1, bid - 64, stage);
    else prep_body<1024>(m2, n2, bid - 128, stage);
}

// ---------- GEMM: BM=64 x BN=1024, 16 waves; B via gload_lds + counted vmcnt
// (2 kb deep, wave-private LDS, NO barrier on B path); A via reg->LDS dbuf
// with lgkm-only barriers. No stores in the K-loop (R4/R8/R14/R19 lesson).
// ALL output streaming (zeros + f-copy) sits AFTER the last __syncthreads:
// waves retire with stores in flight; drain overlaps the next block's K-loop.
template<int C>
__device__ __forceinline__ void gemm_body(const float* __restrict__ feat,
                                          const float* __restrict__ memv,
                                          const short* __restrict__ nm,
                                          float* __restrict__ out_cat,
                                          float* __restrict__ out_w,
                                          int tile,
                                          short* __restrict__ Bst,   // 2 x 32768 shorts
                                          short* __restrict__ As,    // 2 x 4096 shorts
                                          float (*__restrict__ red)[64],
                                          float* __restrict__ rowT,
                                          float* __restrict__ rowL,
                                          float* __restrict__ invL,
                                          int* __restrict__ rowflag,
                                          int* __restrict__ anyflag) {
    constexpr int NKB = C / 32;          // MFMA K-steps
    constexpr int NCH = C / 64;          // A LDS chunks (64 k each)
    const int tid  = threadIdx.x;        // 0..1023
    const int w    = tid >> 6;           // wave 0..15
    const int lane = tid & 63;
    const int g    = lane >> 4;
    const int ml   = lane & 15;
    const int swz  = ml & 7;
    const int row0 = tile * 64;

    // A fill role: thread -> (row 0..63, f32x4 slot 0..15 of a 64-float chunk)
    const int frow = tid >> 4;
    const int fk4  = tid & 15;
    const float* fsrc = feat + (size_t)(row0 + frow) * C + fk4 * 4;
    const int ldsW = frow * 64 + (((fk4 >> 1) ^ (frow & 7)) << 3) + (fk4 & 1) * 4;
    // B: wave w owns col-tiles w*4..w*4+3; wave-private LDS frags of 1 KB
    const short* nbG = nm + (size_t)(w * 4) * NKB * 512 + lane * 8;
    short* bD0 = Bst + (w * 4) * 512 + lane * 8;
    short* bD1 = Bst + 32768 + (w * 4) * 512 + lane * 8;

    if (tid == 0) *anyflag = 0;

    f32x4 acc[4][4];
#pragma unroll
    for (int r = 0; r < 4; ++r)
#pragma unroll
        for (int ct = 0; ct < 4; ++ct)
            acc[r][ct] = (f32x4){0.f, 0.f, 0.f, 0.f};

    float ss = 0.f;

    // ---- prologue: stage B kb0->buf0, kb1->buf1 (8 DMAs in flight) ----
#pragma unroll
    for (int p = 0; p < 4; ++p)
        g2l16(nbG + (size_t)p * NKB * 512, bD0 + p * 512);
#pragma unroll
    for (int p = 0; p < 4; ++p)
        g2l16(nbG + ((size_t)p * NKB + 1) * 512, bD1 + p * 512);
    // A chunk0 via regs, prefetch chunk1
    {
        const f32x4 v = *(const f32x4*)fsrc;
        ss += v.x * v.x + v.y * v.y + v.z * v.z + v.w * v.w;
        s16x4 o;
        o[0] = (short)f2bf(v.x); o[1] = (short)f2bf(v.y);
        o[2] = (short)f2bf(v.z); o[3] = (short)f2bf(v.w);
        *(s16x4*)&As[ldsW] = o;
    }
    f32x4 fnxt;
    if (NCH > 1) fnxt = *(const f32x4*)(fsrc + 64);
    asm volatile("s_waitcnt lgkmcnt(0)" ::: "memory");
    __builtin_amdgcn_s_barrier();
    asm volatile("" ::: "memory");

    // ---- K loop (no stores anywhere in here) ----
    for (int kb = 0; kb < NKB; ++kb) {
        const int chunk = kb >> 1;
        if ((kb & 1) == 0 && chunk + 1 < NCH) {
            // fill next A chunk from prefetched regs
            ss += fnxt.x * fnxt.x + fnxt.y * fnxt.y + fnxt.z * fnxt.z + fnxt.w * fnxt.w;
            s16x4 o;
            o[0] = (short)f2bf(fnxt.x); o[1] = (short)f2bf(fnxt.y);
            o[2] = (short)f2bf(fnxt.z); o[3] = (short)f2bf(fnxt.w);
            *(s16x4*)&As[((chunk + 1) & 1) * 4096 + ldsW] = o;
            if (chunk + 2 < NCH)
                fnxt = *(const f32x4*)(fsrc + (size_t)(chunk + 2) * 64);
        }
        // wait this kb's 4 DMAs (counted: kb+1's stay in flight)
        if (kb < NKB - 1) asm volatile("s_waitcnt vmcnt(4)" ::: "memory");
        else              asm volatile("s_waitcnt vmcnt(0)" ::: "memory");
        // read own B frags + A frags from LDS
        const short* Bb = Bst + (kb & 1) * 32768 + (w * 4) * 512 + lane * 8;
        s16x8 b[4];
#pragma unroll
        for (int p = 0; p < 4; ++p)
            b[p] = *(const s16x8*)(Bb + p * 512);
        const short* Ab = &As[(chunk & 1) * 4096];
        const int gr = ((kb & 1) << 2) | g;
        s16x8 a[4];
#pragma unroll
        for (int r = 0; r < 4; ++r)
            a[r] = *(const s16x8*)&Ab[(r * 16 + ml) * 64 + ((gr ^ swz) << 3)];
        // drain LDS reads, then reuse this B buffer for kb+2's DMA
        asm volatile("s_waitcnt lgkmcnt(0)" ::: "memory");
        __builtin_amdgcn_sched_barrier(0);
        if (kb + 2 < NKB) {
            short* bDn = Bst + (kb & 1) * 32768 + (w * 4) * 512 + lane * 8;
#pragma unroll
            for (int p = 0; p < 4; ++p)
                g2l16(nbG + ((size_t)p * NKB + kb + 2) * 512, bDn + p * 512);
        }
        __builtin_amdgcn_s_setprio(1);
#pragma unroll
        for (int r = 0; r < 4; ++r)
#pragma unroll
            for (int ct = 0; ct < 4; ++ct)
                acc[r][ct] = __builtin_amdgcn_mfma_f32_16x16x32_bf16(a[r], b[ct], acc[r][ct], 0, 0, 0);
        __builtin_amdgcn_s_setprio(0);
        // A barrier after odd kb (lgkm-only; B DMAs stay in flight)
        if ((kb & 1) == 1 && kb + 1 < NKB) {
            asm volatile("s_waitcnt lgkmcnt(0)" ::: "memory");
            __builtin_amdgcn_s_barrier();
            asm volatile("" ::: "memory");
        }
    }

    // ---- invn from own staged data ----
#pragma unroll
    for (int m = 1; m < 16; m <<= 1) ss += __shfl_xor(ss, m);
    if (fk4 == 0) invL[frow] = 1.f / fmaxf(sqrtf(ss), 1e-12f);
    __syncthreads();

    // C/D: global row = r*16 + 4*g + i, global col = (w*4+ct)*16 + ml
    // ---- exp (|cos|<=1: no max-sub) + row sums ----
#pragma unroll
    for (int r = 0; r < 4; ++r)
#pragma unroll
        for (int i = 0; i < 4; ++i) {
            const float inv = invL[r * 16 + 4 * g + i];
            float s = 0.f;
#pragma unroll
            for (int ct = 0; ct < 4; ++ct) {
                const float e = __expf(acc[r][ct][i] * inv);
                acc[r][ct][i] = e;
                s += e;
            }
#pragma unroll
            for (int m = 1; m < 16; m <<= 1) s += __shfl_xor(s, m);
            if (ml == 0) red[w][r * 16 + 4 * g + i] = s;
        }
    __syncthreads();
    if (tid < 64) {
        float t = red[0][tid];
#pragma unroll
        for (int ww = 1; ww < 16; ++ww) t += red[ww][tid];
        rowT[tid] = 1.f / t;
    }
    __syncthreads();

    // ---- softmax weight, hard-shrink, row L1 ----
#pragma unroll
    for (int r = 0; r < 4; ++r)
#pragma unroll
        for (int i = 0; i < 4; ++i) {
            const float tinv = rowT[r * 16 + 4 * g + i];
            float l1 = 0.f;
#pragma unroll
            for (int ct = 0; ct < 4; ++ct) {
                const float wv = acc[r][ct][i] * tinv;
                const float d = wv - 0.0025f;
                const float v = (d > 0.f) ? (d * wv / (d + 1e-12f)) : 0.f;
                acc[r][ct][i] = v;
                l1 += v;
            }
#pragma unroll
            for (int m = 1; m < 16; m <<= 1) l1 += __shfl_xor(l1, m);
            if (ml == 0) red[w][r * 16 + 4 * g + i] = l1;
        }
    __syncthreads();
    if (tid < 64) {
        float t = red[0][tid];
#pragma unroll
        for (int ww = 1; ww < 16; ++ww) t += red[ww][tid];
        rowL[tid] = 1.f / fmaxf(t, 1e-12f);
        rowflag[tid] = (t > 0.f) ? 1 : 0;
        if (t > 0.f) *anyflag = 1;
    }
    __syncthreads();                     // LAST barrier of the common path

    // ---- store W (normal cached stores; L2 assembles full lines) ----
#pragma unroll
    for (int r = 0; r < 4; ++r)
#pragma unroll
        for (int i = 0; i < 4; ++i) {
            const float il = rowL[r * 16 + 4 * g + i];
            float* orow = out_w + (size_t)(row0 + r * 16 + 4 * g + i) * 1024;
#pragma unroll
            for (int ct = 0; ct < 4; ++ct)
                orow[(w * 4 + ct) * 16 + ml] = acc[r][ct][i] * il;
        }

    // ---- TAIL streaming: mf zeros + f-copy (f L2/L3-hot). Nothing below
    // waits on vmcnt in the common path -> waves retire with the whole write
    // retinue in flight; it drains under the next block's K-loop. ----
    {
        float* fzro = out_cat + (size_t)(row0 + frow) * (2 * C) + fk4 * 4;
        float* fcpy = out_cat + (size_t)(row0 + frow) * (2 * C) + C + fk4 * 4;
        const f32x4 z4 = {0.f, 0.f, 0.f, 0.f};
#pragma unroll
        for (int ch = 0; ch < NCH; ++ch)
            __builtin_nontemporal_store(z4, (f32x4*)(fzro + (size_t)ch * 64));
#pragma unroll
        for (int ch = 0; ch < NCH; ++ch) {
            const f32x4 v = *(const f32x4*)(fsrc + (size_t)ch * 64);
            __builtin_nontemporal_store(v, (f32x4*)(fcpy + (size_t)ch * 64));
        }
    }

    // ---- mf fixup ONLY when a row survived the shrink (rare path) ----
    if (*anyflag != 0) {
        __threadfence();
        __syncthreads();
        constexpr int CC = C / 64;
#pragma unroll
        for (int rr = 0; rr < 4; ++rr) {
            const int row = w * 4 + rr;
            if (!rowflag[row]) continue;
            float* dst = out_cat + (size_t)(row0 + row) * (2 * C);
            float mfacc[CC];
#pragma unroll
            for (int cc = 0; cc < CC; ++cc) mfacc[cc] = 0.f;
            const float* wrow = out_w + (size_t)(row0 + row) * 1024;
            for (int jb = 0; jb < 1024; jb += 64) {
                const float wv = wrow[jb + lane];
                unsigned long long msk = __ballot(wv != 0.f);
                while (msk) {
                    const int j = __builtin_ctzll(msk);
                    msk &= msk - 1;
                    const float val = __shfl(wv, j);
                    const float* mrow = memv + (size_t)(jb + j) * C;
#pragma unroll
                    for (int cc = 0; cc < CC; ++cc)
                        mfacc[cc] += val * mrow[cc * 64 + lane];
                }
            }
#pragma unroll
            for (int cc = 0; cc < CC; ++cc) dst[cc * 64 + lane] = mfacc[cc];
        }
    }
}

// unit-sorted: unit2 first (nm2 L2-hot), then unit1, unit0
__global__ __launch_bounds__(1024) void gemm_all(
        const float* f0, const float* m0, const short* n0, float* o0, float* w0,
        const float* f1, const float* m1, const short* n1, float* o1, float* w1,
        const float* f2, const float* m2, const short* n2, float* o2, float* w2) {
    __shared__ short Bst[2 * 32768];     // 2 x 64 KB B k-slabs (wave-private frags)
    __shared__ short As[2 * 4096];       // 2 x 8 KB A chunks
    __shared__ float red[16][64];
    __shared__ float rowT[64];
    __shared__ float rowL[64];
    __shared__ float invL[64];
    __shared__ int rowflag[64];
    __shared__ int anyflag;

    const int bid = blockIdx.x;
    if (bid < 256)
        gemm_body<1024>(f2, m2, n2, o2, w2, bid,
                        Bst, As, red, rowT, rowL, invL, rowflag, &anyflag);
    else if (bid < 512)
        gemm_body<512>(f1, m1, n1, o1, w1, bid - 256,
                       Bst, As, red, rowT, rowL, invL, rowflag, &anyflag);
    else
        gemm_body<256>(f0, m0, n0, o0, w0, bid - 512,
                       Bst, As, red, rowT, rowL, invL, rowflag, &anyflag);
}

extern "C" void kernel_launch(void* const* d_in, const int* in_sizes, int n_in,
                              void* d_out, int out_size, void* d_ws, size_t ws_size,
                              hipStream_t stream) {
    const float* feat[3] = {nullptr, nullptr, nullptr};
    const float* memp[3] = {nullptr, nullptr, nullptr};
    for (int i = 0; i < n_in && i < 6; ++i) {
        const int s = in_sizes[i];
        const float* p = (const float*)d_in[i];
        if (s == 16384 * 256) feat[0] = p;
        else if (s == 16384 * 512) feat[1] = p;
        else if (s == 16384 * 1024) feat[2] = p;
        else if (s == 1024 * 256) memp[0] = p;
        else if (s == 1024 * 512) memp[1] = p;
        else if (s == 1024 * 1024) memp[2] = p;
    }
    float* out = (float*)d_out;
    short* nm0 = (short*)d_ws;
    short* nm1 = nm0 + 1024 * 256;
    short* nm2 = nm1 + 1024 * 512;

    // output layout (floats): out0 | out1 | out2 | w0 | w1 | w2
    const size_t O0 = 0;
    const size_t O1 = (size_t)16384 * 512;
    const size_t O2 = O1 + (size_t)16384 * 1024;
    const size_t W0 = O2 + (size_t)16384 * 2048;
    const size_t W1 = W0 + (size_t)16384 * 1024;
    const size_t W2 = W1 + (size_t)16384 * 1024;

    prep_all<<<192, 256, 0, stream>>>(memp[0], nm0, memp[1], nm1, memp[2], nm2);

    gemm_all<<<768, 1024, 0, stream>>>(
        feat[0], memp[0], nm0, out + O0, out + W0,
        feat[1], memp[1], nm1, out + O1, out + W1,
        feat[2], memp[2], nm2, out + O2, out + W2);
}